// Round 17
// baseline (469.676 us; speedup 1.0000x reference)
//
#include <hip/hip_runtime.h>
#include <hip/hip_bf16.h>

#define NN 50000
#define NE 500000
#define NTILES ((NE + 63) / 64)
#define NTILEN ((NN + 63) / 64)
#define SCAN_BLK 49   // ceil(NN / 1024)
#define QKV_BLOCKS 782
#define HIST_BLOCKS ((NE + 255) / 256)

typedef __hip_bfloat16 bf16;
typedef short s16x8 __attribute__((ext_vector_type(8)));
typedef float f32x4 __attribute__((ext_vector_type(4)));

__device__ __forceinline__ float wave_sum(float v) {
#pragma unroll
  for (int o = 32; o >= 1; o >>= 1) v += __shfl_xor(v, o);
  return v;
}

__device__ __forceinline__ unsigned short f2bf(float f) {
  __hip_bfloat16 h = __float2bfloat16(f);
  return __builtin_bit_cast(unsigned short, h);
}

__device__ __forceinline__ float bf2f(unsigned short u) {
  union { unsigned u; float f; } v; v.u = ((unsigned)u) << 16;
  return v.f;
}

// ---------------- QKV (MFMA, split-x) + fused hist (independent blocks) ----------------
__global__ __launch_bounds__(256, 4) void qkv_hist_kernel(
    const float* __restrict__ x,
    const float* __restrict__ Wq, const float* __restrict__ bq,
    const float* __restrict__ Wk, const float* __restrict__ bk,
    const float* __restrict__ Wv, const float* __restrict__ bv,
    unsigned short* __restrict__ Qh, unsigned short* __restrict__ Kh,
    unsigned short* __restrict__ Vh,
    const int* __restrict__ eidx, int* __restrict__ cnt) {
  if (blockIdx.x >= QKV_BLOCKS) {
    int i = (blockIdx.x - QKV_BLOCKS) * 256 + threadIdx.x;
    if (i < NE) atomicAdd(&cnt[eidx[NE + i]], 1);
    return;
  }
  __shared__ unsigned short sXhi[64][72];
  __shared__ unsigned short sXlo[64][72];
  const int tid = threadIdx.x;
  const int lane = tid & 63;
  const int w = tid >> 6;
  const int c15 = lane & 15;
  const int q = lane >> 4;
  const int klo = q * 8;
  const int g16 = lane >> 4;
  const int l16 = lane & 15;

  const float* Wsel[3] = {Wq, Wk, Wv};
  const float* bsel[3] = {bq, bk, bv};
  unsigned short* osel[3] = {Qh, Kh, Vh};
  const int col = w * 16 + c15;

  s16x8 bf[3][2];
#pragma unroll
  for (int j = 0; j < 3; ++j) {
#pragma unroll
    for (int kh = 0; kh < 2; ++kh) {
      s16x8 tmp;
#pragma unroll
      for (int i = 0; i < 8; ++i) tmp[i] = (short)f2bf(Wsel[j][(kh * 32 + klo + i) * 64 + col]);
      bf[j][kh] = tmp;
    }
  }
  float bias_r[3];
#pragma unroll
  for (int j = 0; j < 3; ++j) bias_r[j] = bsel[j][col];

  for (int T = blockIdx.x; T < NTILEN; T += QKV_BLOCKS) {
    const int N0 = T * 64;
#pragma unroll
    for (int it = 0; it < 4; ++it) {
      int r = it * 16 + w * 4 + g16;
      int n = N0 + r;
      float4 xv = {0.f, 0.f, 0.f, 0.f};
      if (n < NN) xv = *(const float4*)&x[(size_t)n * 64 + l16 * 4];
      ushort4 h4, l4;
      h4.x = f2bf(xv.x); l4.x = f2bf(xv.x - bf2f(h4.x));
      h4.y = f2bf(xv.y); l4.y = f2bf(xv.y - bf2f(h4.y));
      h4.z = f2bf(xv.z); l4.z = f2bf(xv.z - bf2f(h4.z));
      h4.w = f2bf(xv.w); l4.w = f2bf(xv.w - bf2f(h4.w));
      *(ushort4*)&sXhi[r][l16 * 4] = h4;
      *(ushort4*)&sXlo[r][l16 * 4] = l4;
    }
    __syncthreads();

    f32x4 acc[4][3];
#pragma unroll
    for (int m = 0; m < 4; ++m)
#pragma unroll
      for (int j = 0; j < 3; ++j) acc[m][j] = (f32x4){0.f, 0.f, 0.f, 0.f};
#pragma unroll
    for (int m = 0; m < 4; ++m) {
      s16x8 h0 = *(const s16x8*)&sXhi[16 * m + c15][klo];
      s16x8 h1 = *(const s16x8*)&sXhi[16 * m + c15][klo + 32];
      s16x8 l0 = *(const s16x8*)&sXlo[16 * m + c15][klo];
      s16x8 l1 = *(const s16x8*)&sXlo[16 * m + c15][klo + 32];
#pragma unroll
      for (int j = 0; j < 3; ++j) {
        acc[m][j] = __builtin_amdgcn_mfma_f32_16x16x32_bf16(h0, bf[j][0], acc[m][j], 0, 0, 0);
        acc[m][j] = __builtin_amdgcn_mfma_f32_16x16x32_bf16(h1, bf[j][1], acc[m][j], 0, 0, 0);
        acc[m][j] = __builtin_amdgcn_mfma_f32_16x16x32_bf16(l0, bf[j][0], acc[m][j], 0, 0, 0);
        acc[m][j] = __builtin_amdgcn_mfma_f32_16x16x32_bf16(l1, bf[j][1], acc[m][j], 0, 0, 0);
      }
    }
#pragma unroll
    for (int m = 0; m < 4; ++m) {
#pragma unroll
      for (int j = 0; j < 3; ++j) {
#pragma unroll
        for (int i = 0; i < 4; ++i) {
          int n = N0 + 16 * m + q * 4 + i;
          if (n < NN) osel[j][(size_t)n * 64 + col] = f2bf(acc[m][j][i] + bias_r[j]);
        }
      }
    }
    __syncthreads();
  }
}

// ---------------- CSR build ----------------
__global__ __launch_bounds__(256) void scan1_kernel(const int* __restrict__ cnt, int* __restrict__ bsum) {
  __shared__ int wsum[4];
  const int t = threadIdx.x;
  const int base = blockIdx.x * 1024 + t * 4;
  int s = 0;
#pragma unroll
  for (int j = 0; j < 4; j++) {
    int i = base + j;
    if (i < NN) s += cnt[i];
  }
#pragma unroll
  for (int o = 1; o < 64; o <<= 1) s += __shfl_xor(s, o);
  if ((t & 63) == 0) wsum[t >> 6] = s;
  __syncthreads();
  if (t == 0) bsum[blockIdx.x] = wsum[0] + wsum[1] + wsum[2] + wsum[3];
}

__global__ __launch_bounds__(64) void scan2_kernel(int* __restrict__ bsum, int* __restrict__ rs) {
  const int t = threadIdx.x;
  int v = (t < SCAN_BLK) ? bsum[t] : 0;
  int s = v;
#pragma unroll
  for (int o = 1; o < 64; o <<= 1) {
    int u = __shfl_up(s, o);
    if (t >= o) s += u;
  }
  if (t < SCAN_BLK) bsum[t] = s - v;
  if (t == 63) rs[NN] = s;
}

__global__ __launch_bounds__(256) void scan3_kernel(int* __restrict__ cnt, const int* __restrict__ bsum,
                                                    int* __restrict__ rs) {
  __shared__ int wsum[4];
  const int t = threadIdx.x;
  const int lane = t & 63, w = t >> 6;
  const int base = blockIdx.x * 1024 + t * 4;
  int v[4];
  int s = 0;
#pragma unroll
  for (int j = 0; j < 4; j++) {
    int i = base + j;
    v[j] = (i < NN) ? cnt[i] : 0;
    s += v[j];
  }
  int inc = s;
#pragma unroll
  for (int o = 1; o < 64; o <<= 1) {
    int u = __shfl_up(inc, o);
    if (lane >= o) inc += u;
  }
  int ex = inc - s;
  int wtot = __shfl(inc, 63);
  if (lane == 0) wsum[w] = wtot;
  __syncthreads();
  int woff = 0;
  for (int i = 0; i < w; i++) woff += wsum[i];
  int off = bsum[blockIdx.x] + woff + ex;
#pragma unroll
  for (int j = 0; j < 4; j++) {
    int i = base + j;
    if (i < NN) {
      rs[i] = off;
      cnt[i] = off;
      off += v[j];
    }
  }
}

// scatter: slot[e] = CSR position; srcs[slot] = src (for node gather)
__global__ __launch_bounds__(256) void scatter_kernel(const int* __restrict__ eidx,
                                                      int* __restrict__ cur,
                                                      int* __restrict__ slot,
                                                      int* __restrict__ srcs) {
  int e = blockIdx.x * 256 + threadIdx.x;
  if (e < NE) {
    int src = eidx[e];
    int dst = eidx[NE + e];
    int p = atomicAdd(&cur[dst], 1);
    slot[e] = p;
    srcs[p] = src;
  }
}

// ---------------- Edge pass (MFMA): Ee GEMM + gate + MFMA-logits + eout GEMM + LN ----------------
__global__ __launch_bounds__(256, 5) void edge_kernel(
    const float* __restrict__ ea,
    const float* __restrict__ We, const float* __restrict__ be,
    const float* __restrict__ Aw,
    const float* __restrict__ Woe, const float* __restrict__ boe,
    const float* __restrict__ ge, const float* __restrict__ bbe,
    const unsigned short* __restrict__ Qh, const unsigned short* __restrict__ Kh,
    const int* __restrict__ eidx, const int* __restrict__ slot,
    unsigned char* __restrict__ sE8, float* __restrict__ exE, float* __restrict__ out_e) {
  __shared__ unsigned short sA[64][72];   // bf16(ea) tile
  __shared__ unsigned short sKQ[64][72];  // bf16(kq) rows -> overwritten with bf16(e_t)
  __shared__ int sSlot[64];

  const int tid = threadIdx.x;
  const int lane = tid & 63;
  const int w = tid >> 6;
  const int c15 = lane & 15;
  const int q = lane >> 4;
  const int klo = q * 8;
  const int g16 = lane >> 4;
  const int l16 = lane & 15;

  s16x8 b1f[2][2], b2f[4][2], bawf[2];
#pragma unroll
  for (int nt = 0; nt < 2; ++nt) {
    int col = (2 * w + nt) * 16 + c15;
#pragma unroll
    for (int kh = 0; kh < 2; ++kh) {
      s16x8 tmp;
#pragma unroll
      for (int i = 0; i < 8; ++i) tmp[i] = (short)f2bf(We[(kh * 32 + klo + i) * 128 + col]);
      b1f[nt][kh] = tmp;
    }
  }
#pragma unroll
  for (int n = 0; n < 4; ++n) {
    int col = n * 16 + c15;
#pragma unroll
    for (int kh = 0; kh < 2; ++kh) {
      s16x8 tmp;
#pragma unroll
      for (int i = 0; i < 8; ++i) tmp[i] = (short)f2bf(Woe[(kh * 32 + klo + i) * 64 + col]);
      b2f[n][kh] = tmp;
    }
  }
  // block-diagonal Aw fragment: B[k][c] = (k>>3 == c) ? Aw[(k&7)*8 + (k>>3)] : 0
#pragma unroll
  for (int kh = 0; kh < 2; ++kh) {
    s16x8 tmp;
#pragma unroll
    for (int i = 0; i < 8; ++i) {
      int k = kh * 32 + klo + i;
      int hh = k >> 3, dd = k & 7;
      tmp[i] = (c15 == hh) ? (short)f2bf(Aw[dd * 8 + hh]) : (short)0;
    }
    bawf[kh] = tmp;
  }
  float be_r[2];
#pragma unroll
  for (int nt = 0; nt < 2; ++nt) be_r[nt] = be[(2 * w + nt) * 16 + c15];
  float boe_r[4], ge_r[4], bbe_r[4];
#pragma unroll
  for (int n = 0; n < 4; ++n) {
    boe_r[n] = boe[n * 16 + c15];
    ge_r[n] = ge[n * 16 + c15];
    bbe_r[n] = bbe[n * 16 + c15];
  }

  for (int T = blockIdx.x; T < NTILES; T += gridDim.x) {
    const int E0 = T * 64;
    // ---- Phase A: stage bf16(ea) + bf16(kq) rows ----
#pragma unroll
    for (int it = 0; it < 4; ++it) {
      int r = it * 16 + w * 4 + g16;
      int e = E0 + r;
      float4 av = {0.f, 0.f, 0.f, 0.f};
      ushort4 kv = {0, 0, 0, 0};
      ushort4 qv = {0, 0, 0, 0};
      int sl = 0;
      if (e < NE) {
        av = *(const float4*)&ea[(size_t)e * 64 + l16 * 4];
        int sn = eidx[e], dn = eidx[NE + e];
        kv = *(const ushort4*)&Kh[(size_t)sn * 64 + l16 * 4];
        qv = *(const ushort4*)&Qh[(size_t)dn * 64 + l16 * 4];
        sl = slot[e];
      }
      ushort4 a4, k4;
      a4.x = f2bf(av.x); a4.y = f2bf(av.y); a4.z = f2bf(av.z); a4.w = f2bf(av.w);
      k4.x = f2bf(bf2f(kv.x) + bf2f(qv.x));
      k4.y = f2bf(bf2f(kv.y) + bf2f(qv.y));
      k4.z = f2bf(bf2f(kv.z) + bf2f(qv.z));
      k4.w = f2bf(bf2f(kv.w) + bf2f(qv.w));
      *(ushort4*)&sA[r][l16 * 4] = a4;
      *(ushort4*)&sKQ[r][l16 * 4] = k4;
      if (l16 == 0) sSlot[r] = sl;
    }
    __syncthreads();

    // ---- Phase B: GEMM1 + gate; e_t overwrites sKQ in place ----
    f32x4 acc[4][2];
#pragma unroll
    for (int m = 0; m < 4; ++m)
#pragma unroll
      for (int nt = 0; nt < 2; ++nt) acc[m][nt] = (f32x4){0.f, 0.f, 0.f, 0.f};
#pragma unroll
    for (int m = 0; m < 4; ++m) {
      s16x8 a0 = *(const s16x8*)&sA[16 * m + c15][klo];
      s16x8 a1 = *(const s16x8*)&sA[16 * m + c15][klo + 32];
#pragma unroll
      for (int nt = 0; nt < 2; ++nt) {
        acc[m][nt] = __builtin_amdgcn_mfma_f32_16x16x32_bf16(a0, b1f[nt][0], acc[m][nt], 0, 0, 0);
        acc[m][nt] = __builtin_amdgcn_mfma_f32_16x16x32_bf16(a1, b1f[nt][1], acc[m][nt], 0, 0, 0);
      }
    }
#pragma unroll
    for (int m = 0; m < 4; ++m) {
#pragma unroll
      for (int nt = 0; nt < 2; ++nt) {
        const int t = 2 * w + nt;
#pragma unroll
        for (int i = 0; i < 4; ++i) {
          int row = 16 * m + q * 4 + i;
          float s = acc[m][nt][i] + be_r[nt];
          float kq = bf2f(sKQ[row][t * 8 + (c15 & 7)]);
          float ks = kq * s;
          float g;
          if (c15 < 8)
            g = copysignf(sqrtf(fabsf(ks) + 1e-8f) - 1e-4f, ks);
          else
            g = s;
          float et = g + __shfl_xor(g, 8);
          if (c15 < 8) sKQ[row][t * 8 + c15] = f2bf(et);
        }
      }
    }
    __syncthreads();

    // ---- Phase C: GEMM2 (wE @ Woe) + MFMA logits + exp + residual + LN + fp8 sE writes ----
    const int rbase = 16 * w;
    f32x4 acc2[4];
    f32x4 acc3 = (f32x4){0.f, 0.f, 0.f, 0.f};
#pragma unroll
    for (int n = 0; n < 4; ++n) acc2[n] = (f32x4){0.f, 0.f, 0.f, 0.f};
    s16x8 wa0 = *(const s16x8*)&sKQ[rbase + c15][klo];
    s16x8 wa1 = *(const s16x8*)&sKQ[rbase + c15][klo + 32];
#pragma unroll
    for (int n = 0; n < 4; ++n) {
      acc2[n] = __builtin_amdgcn_mfma_f32_16x16x32_bf16(wa0, b2f[n][0], acc2[n], 0, 0, 0);
      acc2[n] = __builtin_amdgcn_mfma_f32_16x16x32_bf16(wa1, b2f[n][1], acc2[n], 0, 0, 0);
    }
    acc3 = __builtin_amdgcn_mfma_f32_16x16x32_bf16(wa0, bawf[0], acc3, 0, 0, 0);
    acc3 = __builtin_amdgcn_mfma_f32_16x16x32_bf16(wa1, bawf[1], acc3, 0, 0, 0);
#pragma unroll
    for (int i = 0; i < 4; ++i) {
      int row = rbase + q * 4 + i;
      int e = E0 + row;
      if (c15 < 8 && e < NE) {
        float pl = fminf(fmaxf(acc3[i], -5.f), 5.f);
        exE[(size_t)sSlot[row] * 8 + c15] = expf(pl);
      }
    }
#pragma unroll
    for (int i = 0; i < 4; ++i) {
      int row = rbase + q * 4 + i;
      int e = E0 + row;
      bool val = e < NE;
      float r1[4];
      float sum = 0.f;
#pragma unroll
      for (int n = 0; n < 4; ++n) {
        float eav = bf2f(sA[row][n * 16 + c15]);
        r1[n] = eav + acc2[n][i] + boe_r[n];
        sum += r1[n];
      }
      sum += __shfl_xor(sum, 1);
      sum += __shfl_xor(sum, 2);
      sum += __shfl_xor(sum, 4);
      sum += __shfl_xor(sum, 8);
      float mean = sum * 0.015625f;
      float dv[4];
      float vs = 0.f;
#pragma unroll
      for (int n = 0; n < 4; ++n) {
        dv[n] = r1[n] - mean;
        vs += dv[n] * dv[n];
      }
      vs += __shfl_xor(vs, 1);
      vs += __shfl_xor(vs, 2);
      vs += __shfl_xor(vs, 4);
      vs += __shfl_xor(vs, 8);
      float inv = rsqrtf(vs * 0.015625f + 1e-5f);
#pragma unroll
      for (int n = 0; n < 4; ++n)
        if (val) out_e[(size_t)e * 64 + n * 16 + c15] = dv[n] * inv * ge_r[n] + bbe_r[n];
    }
    // fp8 sE: 4 rows/wave-iter, 16 lanes × 4 B per row (coalesced 64 B)
#pragma unroll
    for (int rr = 0; rr < 4; ++rr) {
      int row = rbase + rr * 4 + q;
      int e = E0 + row;
      if (e < NE) {
        unsigned two01 = *(const unsigned*)&sKQ[row][c15 * 4];
        unsigned two23 = *(const unsigned*)&sKQ[row][c15 * 4 + 2];
        float f0 = bf2f((unsigned short)(two01 & 0xffffu));
        float f1 = bf2f((unsigned short)(two01 >> 16));
        float f2 = bf2f((unsigned short)(two23 & 0xffffu));
        float f3 = bf2f((unsigned short)(two23 >> 16));
        unsigned pk = 0;
        pk = __builtin_amdgcn_cvt_pk_fp8_f32(f0, f1, pk, false);
        pk = __builtin_amdgcn_cvt_pk_fp8_f32(f2, f3, pk, true);
        *(unsigned*)&sE8[(size_t)sSlot[row] * 64 + c15 * 4] = pk;
      }
    }
    __syncthreads();
  }
}

// ---------------- Node gather + epi1 (grid-strided): softmax agg + VeRow + deg + Woh GEMV + LN1 ----------------
__global__ __launch_bounds__(256) void node_gather_kernel(
    const unsigned short* __restrict__ Vh, const unsigned char* __restrict__ sE8,
    const float* __restrict__ exE,
    const int* __restrict__ srcs, const int* __restrict__ rs,
    const float* __restrict__ VeRow, const float* __restrict__ deg_coef,
    const float* __restrict__ log_deg,
    const float* __restrict__ x,
    const float* __restrict__ Woh, const float* __restrict__ boh,
    const float* __restrict__ g1, const float* __restrict__ bb1,
    float* __restrict__ h1out) {
  __shared__ float VeL[512];
  __shared__ float dcL[128];
  __shared__ float WohL[4096];
  __shared__ float sb[192];  // boh | g1 | bb1
  const int tid = threadIdx.x;
  for (int i = tid; i < 512; i += 256) VeL[i] = VeRow[i];
  if (tid < 128) dcL[tid] = deg_coef[tid];
  for (int i = tid; i < 4096; i += 256) WohL[i] = Woh[i];
  if (tid < 64) { sb[tid] = boh[tid]; sb[64 + tid] = g1[tid]; sb[128 + tid] = bb1[tid]; }
  __syncthreads();
  const int lane = tid & 63;
  const int wv_id = tid >> 6;
  for (int n = blockIdx.x * 4 + wv_id; n < NN; n += gridDim.x * 4) {
    const int beg = rs[n], end = rs[n + 1];
    const int h = lane >> 3;
    float den = 0.f, wv = 0.f, rv = 0.f;
#pragma unroll 4
    for (int i = beg; i < end; i++) {
      float ex = exE[(size_t)i * 8 + h];
      float v = bf2f(Vh[(size_t)srcs[i] * 64 + lane]);
      unsigned b = sE8[(size_t)i * 64 + lane];
      float sv = __builtin_amdgcn_cvt_f32_fp8(b, 0);
      den += ex;
      wv = fmaf(ex, v, wv);
      rv = fmaf(ex, sv, rv);
    }
    float inv = 1.f / (den + 1e-16f);
    wv *= inv;
    rv *= inv;
#pragma unroll
    for (int d2 = 0; d2 < 8; d2++) {
      float r = __shfl(rv, (lane & 56) + d2);
      wv = fmaf(r, VeL[d2 * 64 + lane], wv);
    }
    float ld = log_deg[n];
    float hv = wv * (dcL[2 * lane] + ld * dcL[2 * lane + 1]);
    float acc = sb[lane];
#pragma unroll 8
    for (int k = 0; k < 64; k++) acc = fmaf(__shfl(hv, k), WohL[k * 64 + lane], acc);
    float r1 = x[(size_t)n * 64 + lane] + acc;
    float m = wave_sum(r1) * 0.015625f;
    float dv = r1 - m;
    float var = wave_sum(dv * dv) * 0.015625f;
    h1out[(size_t)n * 64 + lane] = dv * rsqrtf(var + 1e-5f) * sb[64 + lane] + sb[128 + lane];
  }
}

// ---------------- Node epilogue 2 (grid-strided): h = LN2(h1 + FFN(h1)) ----------------
__global__ __launch_bounds__(256, 4) void node_epi2_kernel(
    const float* __restrict__ W1, const float* __restrict__ b1,
    const float* __restrict__ W2, const float* __restrict__ b2,
    const float* __restrict__ g2, const float* __restrict__ bb2,
    float* __restrict__ hio) {
  extern __shared__ float sm[];
  float* W1L = sm;
  float* W2L = sm + 8192;
  float* sb = sm + 16384;
  const int tid = threadIdx.x;
  for (int i = tid; i < 8192; i += 256) { W1L[i] = W1[i]; W2L[i] = W2[i]; }
  if (tid < 128) sb[tid] = b1[tid];
  if (tid < 64) { sb[128 + tid] = b2[tid]; sb[192 + tid] = g2[tid]; sb[256 + tid] = bb2[tid]; }
  __syncthreads();
  const int lane = tid & 63;
  for (int nb = blockIdx.x * 16; nb < NN; nb += gridDim.x * 16) {
    const int n0 = nb + (tid >> 6) * 4;
    float h1[4];
#pragma unroll
    for (int j = 0; j < 4; j++)
      h1[j] = (n0 + j < NN) ? hio[(size_t)(n0 + j) * 64 + lane] : 0.f;
    float ua[4], ub[4];
#pragma unroll
    for (int j = 0; j < 4; j++) { ua[j] = sb[lane]; ub[j] = sb[64 + lane]; }
#pragma unroll 4
    for (int k = 0; k < 64; k++) {
      float wa = W1L[k * 128 + lane];
      float wb = W1L[k * 128 + 64 + lane];
#pragma unroll
      for (int j = 0; j < 4; j++) {
        float w = __shfl(h1[j], k);
        ua[j] = fmaf(w, wa, ua[j]);
        ub[j] = fmaf(w, wb, ub[j]);
      }
    }
    float a2[4];
#pragma unroll
    for (int j = 0; j < 4; j++) {
      ua[j] = fmaxf(ua[j], 0.f);
      ub[j] = fmaxf(ub[j], 0.f);
      a2[j] = sb[128 + lane];
    }
#pragma unroll 4
    for (int k = 0; k < 64; k++) {
      float wa = W2L[k * 64 + lane];
      float wb = W2L[(64 + k) * 64 + lane];
#pragma unroll
      for (int j = 0; j < 4; j++) {
        a2[j] = fmaf(__shfl(ua[j], k), wa, a2[j]);
        a2[j] = fmaf(__shfl(ub[j], k), wb, a2[j]);
      }
    }
#pragma unroll
    for (int j = 0; j < 4; j++) {
      if (n0 + j >= NN) continue;
      float r2 = h1[j] + a2[j];
      float m = wave_sum(r2) * 0.015625f;
      float dv = r2 - m;
      float var = wave_sum(dv * dv) * 0.015625f;
      hio[(size_t)(n0 + j) * 64 + lane] = dv * rsqrtf(var + 1e-5f) * sb[192 + lane] + sb[256 + lane];
    }
  }
}

extern "C" void kernel_launch(void* const* d_in, const int* in_sizes, int n_in,
                              void* d_out, int out_size, void* d_ws, size_t ws_size,
                              hipStream_t stream) {
  const float* x = (const float*)d_in[0];
  const float* ea = (const float*)d_in[1];
  const float* log_deg = (const float*)d_in[2];
  const float* Wq = (const float*)d_in[3];
  const float* bq = (const float*)d_in[4];
  const float* Wk = (const float*)d_in[5];
  const float* bk = (const float*)d_in[6];
  const float* Wv = (const float*)d_in[7];
  const float* bv = (const float*)d_in[8];
  const float* We = (const float*)d_in[9];
  const float* be = (const float*)d_in[10];
  const float* Aw = (const float*)d_in[11];
  const float* VeRow = (const float*)d_in[12];
  const float* deg_coef = (const float*)d_in[13];
  const float* Woh = (const float*)d_in[14];
  const float* boh = (const float*)d_in[15];
  const float* Woe = (const float*)d_in[16];
  const float* boe = (const float*)d_in[17];
  const float* g1h = (const float*)d_in[18];
  const float* b1h = (const float*)d_in[19];
  const float* g1e = (const float*)d_in[20];
  const float* b1e = (const float*)d_in[21];
  const float* W1 = (const float*)d_in[22];
  const float* b1 = (const float*)d_in[23];
  const float* W2 = (const float*)d_in[24];
  const float* b2 = (const float*)d_in[25];
  const float* g2h = (const float*)d_in[26];
  const float* b2h = (const float*)d_in[27];
  const int* eidx = (const int*)d_in[28];

  char* p = (char*)d_ws;
  unsigned short* Qh = (unsigned short*)p; p += (size_t)NN * 64 * 2;
  unsigned short* Kh = (unsigned short*)p; p += (size_t)NN * 64 * 2;
  unsigned short* Vh = (unsigned short*)p; p += (size_t)NN * 64 * 2;
  unsigned char* sE8 = (unsigned char*)p; p += (size_t)NE * 64;
  float* exE = (float*)p; p += (size_t)NE * 8 * 4;
  int* cnt = (int*)p;   p += ((size_t)NN * 4 + 255) & ~(size_t)255;
  int* rs = (int*)p;    p += (((size_t)NN + 1) * 4 + 255) & ~(size_t)255;
  int* slot = (int*)p;  p += (size_t)NE * 4;
  int* srcs = (int*)p;  p += (size_t)NE * 4;
  int* bsum = (int*)p;  p += ((size_t)SCAN_BLK * 4 + 255) & ~(size_t)255;
  if ((size_t)(p - (char*)d_ws) > ws_size) return;

  float* out_h = (float*)d_out;
  float* out_e = out_h + (size_t)NN * 64;

  hipMemsetAsync(cnt, 0, NN * sizeof(int), stream);
  qkv_hist_kernel<<<QKV_BLOCKS + HIST_BLOCKS, 256, 0, stream>>>(
      x, Wq, bq, Wk, bk, Wv, bv, Qh, Kh, Vh, eidx, cnt);
  scan1_kernel<<<SCAN_BLK, 256, 0, stream>>>(cnt, bsum);
  scan2_kernel<<<1, 64, 0, stream>>>(bsum, rs);
  scan3_kernel<<<SCAN_BLK, 256, 0, stream>>>(cnt, bsum, rs);
  scatter_kernel<<<(NE + 255) / 256, 256, 0, stream>>>(eidx, cnt, slot, srcs);
  edge_kernel<<<1280, 256, 0, stream>>>(ea, We, be, Aw, Woe, boe, g1e, b1e,
                                        Qh, Kh, eidx, slot, sE8, exE, out_e);
  node_gather_kernel<<<1024, 256, 0, stream>>>(Vh, sE8, exE, srcs, rs, VeRow,
                                               deg_coef, log_deg,
                                               x, Woh, boh, g1h, b1h, out_h);
  node_epi2_kernel<<<512, 256, 16704 * 4, stream>>>(W1, b1, W2, b2, g2h, b2h, out_h);
}

// Round 18
// 467.491 us; speedup vs baseline: 1.0047x; 1.0047x over previous
//
#include <hip/hip_runtime.h>
#include <hip/hip_bf16.h>

#define NN 50000
#define NE 500000
#define NTILES ((NE + 63) / 64)
#define NTILEN ((NN + 63) / 64)
#define SCAN_BLK 49   // ceil(NN / 1024)
#define QKV_BLOCKS 782
#define HIST_BLOCKS ((NE + 255) / 256)

typedef __hip_bfloat16 bf16;
typedef short s16x8 __attribute__((ext_vector_type(8)));
typedef float f32x4 __attribute__((ext_vector_type(4)));

__device__ __forceinline__ float wave_sum(float v) {
#pragma unroll
  for (int o = 32; o >= 1; o >>= 1) v += __shfl_xor(v, o);
  return v;
}

__device__ __forceinline__ unsigned short f2bf(float f) {
  __hip_bfloat16 h = __float2bfloat16(f);
  return __builtin_bit_cast(unsigned short, h);
}

__device__ __forceinline__ float bf2f(unsigned short u) {
  union { unsigned u; float f; } v; v.u = ((unsigned)u) << 16;
  return v.f;
}

// ---------------- QKV (MFMA, split-x) + fused hist (independent blocks) ----------------
__global__ __launch_bounds__(256, 4) void qkv_hist_kernel(
    const float* __restrict__ x,
    const float* __restrict__ Wq, const float* __restrict__ bq,
    const float* __restrict__ Wk, const float* __restrict__ bk,
    const float* __restrict__ Wv, const float* __restrict__ bv,
    unsigned short* __restrict__ Qh, unsigned short* __restrict__ Kh,
    unsigned short* __restrict__ Vh,
    const int* __restrict__ eidx, int* __restrict__ cnt) {
  if (blockIdx.x >= QKV_BLOCKS) {
    // hist part: runs concurrently with qkv on remaining blocks
    int i = (blockIdx.x - QKV_BLOCKS) * 256 + threadIdx.x;
    if (i < NE) atomicAdd(&cnt[eidx[NE + i]], 1);
    return;
  }
  __shared__ unsigned short sXhi[64][72];
  __shared__ unsigned short sXlo[64][72];
  const int tid = threadIdx.x;
  const int lane = tid & 63;
  const int w = tid >> 6;
  const int c15 = lane & 15;
  const int q = lane >> 4;
  const int klo = q * 8;
  const int g16 = lane >> 4;
  const int l16 = lane & 15;

  const float* Wsel[3] = {Wq, Wk, Wv};
  const float* bsel[3] = {bq, bk, bv};
  unsigned short* osel[3] = {Qh, Kh, Vh};
  const int col = w * 16 + c15;

  s16x8 bf[3][2];
#pragma unroll
  for (int j = 0; j < 3; ++j) {
#pragma unroll
    for (int kh = 0; kh < 2; ++kh) {
      s16x8 tmp;
#pragma unroll
      for (int i = 0; i < 8; ++i) tmp[i] = (short)f2bf(Wsel[j][(kh * 32 + klo + i) * 64 + col]);
      bf[j][kh] = tmp;
    }
  }
  float bias_r[3];
#pragma unroll
  for (int j = 0; j < 3; ++j) bias_r[j] = bsel[j][col];

  for (int T = blockIdx.x; T < NTILEN; T += QKV_BLOCKS) {
    const int N0 = T * 64;
#pragma unroll
    for (int it = 0; it < 4; ++it) {
      int r = it * 16 + w * 4 + g16;
      int n = N0 + r;
      float4 xv = {0.f, 0.f, 0.f, 0.f};
      if (n < NN) xv = *(const float4*)&x[(size_t)n * 64 + l16 * 4];
      ushort4 h4, l4;
      h4.x = f2bf(xv.x); l4.x = f2bf(xv.x - bf2f(h4.x));
      h4.y = f2bf(xv.y); l4.y = f2bf(xv.y - bf2f(h4.y));
      h4.z = f2bf(xv.z); l4.z = f2bf(xv.z - bf2f(h4.z));
      h4.w = f2bf(xv.w); l4.w = f2bf(xv.w - bf2f(h4.w));
      *(ushort4*)&sXhi[r][l16 * 4] = h4;
      *(ushort4*)&sXlo[r][l16 * 4] = l4;
    }
    __syncthreads();

    f32x4 acc[4][3];
#pragma unroll
    for (int m = 0; m < 4; ++m)
#pragma unroll
      for (int j = 0; j < 3; ++j) acc[m][j] = (f32x4){0.f, 0.f, 0.f, 0.f};
#pragma unroll
    for (int m = 0; m < 4; ++m) {
      s16x8 h0 = *(const s16x8*)&sXhi[16 * m + c15][klo];
      s16x8 h1 = *(const s16x8*)&sXhi[16 * m + c15][klo + 32];
      s16x8 l0 = *(const s16x8*)&sXlo[16 * m + c15][klo];
      s16x8 l1 = *(const s16x8*)&sXlo[16 * m + c15][klo + 32];
#pragma unroll
      for (int j = 0; j < 3; ++j) {
        acc[m][j] = __builtin_amdgcn_mfma_f32_16x16x32_bf16(h0, bf[j][0], acc[m][j], 0, 0, 0);
        acc[m][j] = __builtin_amdgcn_mfma_f32_16x16x32_bf16(h1, bf[j][1], acc[m][j], 0, 0, 0);
        acc[m][j] = __builtin_amdgcn_mfma_f32_16x16x32_bf16(l0, bf[j][0], acc[m][j], 0, 0, 0);
        acc[m][j] = __builtin_amdgcn_mfma_f32_16x16x32_bf16(l1, bf[j][1], acc[m][j], 0, 0, 0);
      }
    }
#pragma unroll
    for (int m = 0; m < 4; ++m) {
#pragma unroll
      for (int j = 0; j < 3; ++j) {
#pragma unroll
        for (int i = 0; i < 4; ++i) {
          int n = N0 + 16 * m + q * 4 + i;
          if (n < NN) osel[j][(size_t)n * 64 + col] = f2bf(acc[m][j][i] + bias_r[j]);
        }
      }
    }
    __syncthreads();
  }
}

// ---------------- CSR build ----------------
__global__ __launch_bounds__(256) void scan1_kernel(const int* __restrict__ cnt, int* __restrict__ bsum) {
  __shared__ int wsum[4];
  const int t = threadIdx.x;
  const int base = blockIdx.x * 1024 + t * 4;
  int s = 0;
#pragma unroll
  for (int j = 0; j < 4; j++) {
    int i = base + j;
    if (i < NN) s += cnt[i];
  }
#pragma unroll
  for (int o = 1; o < 64; o <<= 1) s += __shfl_xor(s, o);
  if ((t & 63) == 0) wsum[t >> 6] = s;
  __syncthreads();
  if (t == 0) bsum[blockIdx.x] = wsum[0] + wsum[1] + wsum[2] + wsum[3];
}

__global__ __launch_bounds__(64) void scan2_kernel(int* __restrict__ bsum, int* __restrict__ rs) {
  const int t = threadIdx.x;
  int v = (t < SCAN_BLK) ? bsum[t] : 0;
  int s = v;
#pragma unroll
  for (int o = 1; o < 64; o <<= 1) {
    int u = __shfl_up(s, o);
    if (t >= o) s += u;
  }
  if (t < SCAN_BLK) bsum[t] = s - v;
  if (t == 63) rs[NN] = s;
}

__global__ __launch_bounds__(256) void scan3_kernel(int* __restrict__ cnt, const int* __restrict__ bsum,
                                                    int* __restrict__ rs) {
  __shared__ int wsum[4];
  const int t = threadIdx.x;
  const int lane = t & 63, w = t >> 6;
  const int base = blockIdx.x * 1024 + t * 4;
  int v[4];
  int s = 0;
#pragma unroll
  for (int j = 0; j < 4; j++) {
    int i = base + j;
    v[j] = (i < NN) ? cnt[i] : 0;
    s += v[j];
  }
  int inc = s;
#pragma unroll
  for (int o = 1; o < 64; o <<= 1) {
    int u = __shfl_up(inc, o);
    if (lane >= o) inc += u;
  }
  int ex = inc - s;
  int wtot = __shfl(inc, 63);
  if (lane == 0) wsum[w] = wtot;
  __syncthreads();
  int woff = 0;
  for (int i = 0; i < w; i++) woff += wsum[i];
  int off = bsum[blockIdx.x] + woff + ex;
#pragma unroll
  for (int j = 0; j < 4; j++) {
    int i = base + j;
    if (i < NN) {
      rs[i] = off;
      cnt[i] = off;
      off += v[j];
    }
  }
}

// scatter: slot[e] = CSR position; srcs[slot] = src (for node gather)
__global__ __launch_bounds__(256) void scatter_kernel(const int* __restrict__ eidx,
                                                      int* __restrict__ cur,
                                                      int* __restrict__ slot,
                                                      int* __restrict__ srcs) {
  int e = blockIdx.x * 256 + threadIdx.x;
  if (e < NE) {
    int src = eidx[e];
    int dst = eidx[NE + e];
    int p = atomicAdd(&cur[dst], 1);
    slot[e] = p;
    srcs[p] = src;
  }
}

// ---------------- Edge pass (MFMA): Ee GEMM + gate + MFMA-logits + eout GEMM + LN ----------------
__global__ __launch_bounds__(256, 5) void edge_kernel(
    const float* __restrict__ ea,
    const float* __restrict__ We, const float* __restrict__ be,
    const float* __restrict__ Aw,
    const float* __restrict__ Woe, const float* __restrict__ boe,
    const float* __restrict__ ge, const float* __restrict__ bbe,
    const unsigned short* __restrict__ Qh, const unsigned short* __restrict__ Kh,
    const int* __restrict__ eidx, const int* __restrict__ slot,
    bf16* __restrict__ sE, float* __restrict__ exE, float* __restrict__ out_e) {
  __shared__ unsigned short sA[64][72];   // bf16(ea) tile
  __shared__ unsigned short sKQ[64][72];  // bf16(kq) rows -> overwritten with bf16(e_t)
  __shared__ int sSlot[64];

  const int tid = threadIdx.x;
  const int lane = tid & 63;
  const int w = tid >> 6;
  const int c15 = lane & 15;
  const int q = lane >> 4;
  const int klo = q * 8;
  const int g16 = lane >> 4;
  const int l16 = lane & 15;

  s16x8 b1f[2][2], b2f[4][2], bawf[2];
#pragma unroll
  for (int nt = 0; nt < 2; ++nt) {
    int col = (2 * w + nt) * 16 + c15;
#pragma unroll
    for (int kh = 0; kh < 2; ++kh) {
      s16x8 tmp;
#pragma unroll
      for (int i = 0; i < 8; ++i) tmp[i] = (short)f2bf(We[(kh * 32 + klo + i) * 128 + col]);
      b1f[nt][kh] = tmp;
    }
  }
#pragma unroll
  for (int n = 0; n < 4; ++n) {
    int col = n * 16 + c15;
#pragma unroll
    for (int kh = 0; kh < 2; ++kh) {
      s16x8 tmp;
#pragma unroll
      for (int i = 0; i < 8; ++i) tmp[i] = (short)f2bf(Woe[(kh * 32 + klo + i) * 64 + col]);
      b2f[n][kh] = tmp;
    }
  }
  // block-diagonal Aw fragment: B[k][c] = (k>>3 == c) ? Aw[(k&7)*8 + (k>>3)] : 0
#pragma unroll
  for (int kh = 0; kh < 2; ++kh) {
    s16x8 tmp;
#pragma unroll
    for (int i = 0; i < 8; ++i) {
      int k = kh * 32 + klo + i;
      int hh = k >> 3, dd = k & 7;
      tmp[i] = (c15 == hh) ? (short)f2bf(Aw[dd * 8 + hh]) : (short)0;
    }
    bawf[kh] = tmp;
  }
  float be_r[2];
#pragma unroll
  for (int nt = 0; nt < 2; ++nt) be_r[nt] = be[(2 * w + nt) * 16 + c15];
  float boe_r[4], ge_r[4], bbe_r[4];
#pragma unroll
  for (int n = 0; n < 4; ++n) {
    boe_r[n] = boe[n * 16 + c15];
    ge_r[n] = ge[n * 16 + c15];
    bbe_r[n] = bbe[n * 16 + c15];
  }

  for (int T = blockIdx.x; T < NTILES; T += gridDim.x) {
    const int E0 = T * 64;
    // ---- Phase A: stage bf16(ea) + bf16(kq) rows ----
#pragma unroll
    for (int it = 0; it < 4; ++it) {
      int r = it * 16 + w * 4 + g16;
      int e = E0 + r;
      float4 av = {0.f, 0.f, 0.f, 0.f};
      ushort4 kv = {0, 0, 0, 0};
      ushort4 qv = {0, 0, 0, 0};
      int sl = 0;
      if (e < NE) {
        av = *(const float4*)&ea[(size_t)e * 64 + l16 * 4];
        int sn = eidx[e], dn = eidx[NE + e];
        kv = *(const ushort4*)&Kh[(size_t)sn * 64 + l16 * 4];
        qv = *(const ushort4*)&Qh[(size_t)dn * 64 + l16 * 4];
        sl = slot[e];
      }
      ushort4 a4, k4;
      a4.x = f2bf(av.x); a4.y = f2bf(av.y); a4.z = f2bf(av.z); a4.w = f2bf(av.w);
      k4.x = f2bf(bf2f(kv.x) + bf2f(qv.x));
      k4.y = f2bf(bf2f(kv.y) + bf2f(qv.y));
      k4.z = f2bf(bf2f(kv.z) + bf2f(qv.z));
      k4.w = f2bf(bf2f(kv.w) + bf2f(qv.w));
      *(ushort4*)&sA[r][l16 * 4] = a4;
      *(ushort4*)&sKQ[r][l16 * 4] = k4;
      if (l16 == 0) sSlot[r] = sl;
    }
    __syncthreads();

    // ---- Phase B: GEMM1 + gate; e_t overwrites sKQ in place ----
    f32x4 acc[4][2];
#pragma unroll
    for (int m = 0; m < 4; ++m)
#pragma unroll
      for (int nt = 0; nt < 2; ++nt) acc[m][nt] = (f32x4){0.f, 0.f, 0.f, 0.f};
#pragma unroll
    for (int m = 0; m < 4; ++m) {
      s16x8 a0 = *(const s16x8*)&sA[16 * m + c15][klo];
      s16x8 a1 = *(const s16x8*)&sA[16 * m + c15][klo + 32];
#pragma unroll
      for (int nt = 0; nt < 2; ++nt) {
        acc[m][nt] = __builtin_amdgcn_mfma_f32_16x16x32_bf16(a0, b1f[nt][0], acc[m][nt], 0, 0, 0);
        acc[m][nt] = __builtin_amdgcn_mfma_f32_16x16x32_bf16(a1, b1f[nt][1], acc[m][nt], 0, 0, 0);
      }
    }
#pragma unroll
    for (int m = 0; m < 4; ++m) {
#pragma unroll
      for (int nt = 0; nt < 2; ++nt) {
        const int t = 2 * w + nt;
#pragma unroll
        for (int i = 0; i < 4; ++i) {
          int row = 16 * m + q * 4 + i;
          float s = acc[m][nt][i] + be_r[nt];
          float kq = bf2f(sKQ[row][t * 8 + (c15 & 7)]);
          float ks = kq * s;
          float g;
          if (c15 < 8)
            g = copysignf(sqrtf(fabsf(ks) + 1e-8f) - 1e-4f, ks);
          else
            g = s;
          float et = g + __shfl_xor(g, 8);
          if (c15 < 8) sKQ[row][t * 8 + c15] = f2bf(et);
        }
      }
    }
    __syncthreads();

    // ---- Phase C: GEMM2 (wE @ Woe) + MFMA logits + exp + residual + LN + sE writes ----
    const int rbase = 16 * w;
    f32x4 acc2[4];
    f32x4 acc3 = (f32x4){0.f, 0.f, 0.f, 0.f};
#pragma unroll
    for (int n = 0; n < 4; ++n) acc2[n] = (f32x4){0.f, 0.f, 0.f, 0.f};
    s16x8 wa0 = *(const s16x8*)&sKQ[rbase + c15][klo];
    s16x8 wa1 = *(const s16x8*)&sKQ[rbase + c15][klo + 32];
#pragma unroll
    for (int n = 0; n < 4; ++n) {
      acc2[n] = __builtin_amdgcn_mfma_f32_16x16x32_bf16(wa0, b2f[n][0], acc2[n], 0, 0, 0);
      acc2[n] = __builtin_amdgcn_mfma_f32_16x16x32_bf16(wa1, b2f[n][1], acc2[n], 0, 0, 0);
    }
    acc3 = __builtin_amdgcn_mfma_f32_16x16x32_bf16(wa0, bawf[0], acc3, 0, 0, 0);
    acc3 = __builtin_amdgcn_mfma_f32_16x16x32_bf16(wa1, bawf[1], acc3, 0, 0, 0);
#pragma unroll
    for (int i = 0; i < 4; ++i) {
      int row = rbase + q * 4 + i;
      int e = E0 + row;
      if (c15 < 8 && e < NE) {
        float pl = fminf(fmaxf(acc3[i], -5.f), 5.f);
        exE[(size_t)sSlot[row] * 8 + c15] = expf(pl);
      }
    }
#pragma unroll
    for (int i = 0; i < 4; ++i) {
      int row = rbase + q * 4 + i;
      int e = E0 + row;
      bool val = e < NE;
      float r1[4];
      float sum = 0.f;
#pragma unroll
      for (int n = 0; n < 4; ++n) {
        float eav = bf2f(sA[row][n * 16 + c15]);
        r1[n] = eav + acc2[n][i] + boe_r[n];
        sum += r1[n];
      }
      sum += __shfl_xor(sum, 1);
      sum += __shfl_xor(sum, 2);
      sum += __shfl_xor(sum, 4);
      sum += __shfl_xor(sum, 8);
      float mean = sum * 0.015625f;
      float dv[4];
      float vs = 0.f;
#pragma unroll
      for (int n = 0; n < 4; ++n) {
        dv[n] = r1[n] - mean;
        vs += dv[n] * dv[n];
      }
      vs += __shfl_xor(vs, 1);
      vs += __shfl_xor(vs, 2);
      vs += __shfl_xor(vs, 4);
      vs += __shfl_xor(vs, 8);
      float inv = rsqrtf(vs * 0.015625f + 1e-5f);
#pragma unroll
      for (int n = 0; n < 4; ++n)
        if (val) out_e[(size_t)e * 64 + n * 16 + c15] = dv[n] * inv * ge_r[n] + bbe_r[n];
    }
#pragma unroll 4
    for (int rr = 0; rr < 16; ++rr) {
      int row = rbase + rr;
      int e = E0 + row;
      if (e < NE && lane < 32) {
        unsigned v2 = *(const unsigned*)&sKQ[row][lane * 2];
        *(unsigned*)((unsigned short*)sE + (size_t)sSlot[row] * 64 + lane * 2) = v2;
      }
    }
    __syncthreads();
  }
}

// ---------------- Node gather + epi1 (grid-strided): softmax agg + VeRow + deg + Woh GEMV + LN1 ----------------
__global__ __launch_bounds__(256) void node_gather_kernel(
    const unsigned short* __restrict__ Vh, const bf16* __restrict__ sE,
    const float* __restrict__ exE,
    const int* __restrict__ srcs, const int* __restrict__ rs,
    const float* __restrict__ VeRow, const float* __restrict__ deg_coef,
    const float* __restrict__ log_deg,
    const float* __restrict__ x,
    const float* __restrict__ Woh, const float* __restrict__ boh,
    const float* __restrict__ g1, const float* __restrict__ bb1,
    float* __restrict__ h1out) {
  __shared__ float VeL[512];
  __shared__ float dcL[128];
  __shared__ float WohL[4096];
  __shared__ float sb[192];  // boh | g1 | bb1
  const int tid = threadIdx.x;
  for (int i = tid; i < 512; i += 256) VeL[i] = VeRow[i];
  if (tid < 128) dcL[tid] = deg_coef[tid];
  for (int i = tid; i < 4096; i += 256) WohL[i] = Woh[i];
  if (tid < 64) { sb[tid] = boh[tid]; sb[64 + tid] = g1[tid]; sb[128 + tid] = bb1[tid]; }
  __syncthreads();
  const int lane = tid & 63;
  const int wv_id = tid >> 6;
  for (int n = blockIdx.x * 4 + wv_id; n < NN; n += gridDim.x * 4) {
    const int beg = rs[n], end = rs[n + 1];
    const int h = lane >> 3;
    float den = 0.f, wv = 0.f, rv = 0.f;
#pragma unroll 4
    for (int i = beg; i < end; i++) {
      float ex = exE[(size_t)i * 8 + h];
      float v = bf2f(Vh[(size_t)srcs[i] * 64 + lane]);
      float sv = __bfloat162float(sE[(size_t)i * 64 + lane]);
      den += ex;
      wv = fmaf(ex, v, wv);
      rv = fmaf(ex, sv, rv);
    }
    float inv = 1.f / (den + 1e-16f);
    wv *= inv;
    rv *= inv;
#pragma unroll
    for (int d2 = 0; d2 < 8; d2++) {
      float r = __shfl(rv, (lane & 56) + d2);
      wv = fmaf(r, VeL[d2 * 64 + lane], wv);
    }
    float ld = log_deg[n];
    float hv = wv * (dcL[2 * lane] + ld * dcL[2 * lane + 1]);
    float acc = sb[lane];
#pragma unroll 8
    for (int k = 0; k < 64; k++) acc = fmaf(__shfl(hv, k), WohL[k * 64 + lane], acc);
    float r1 = x[(size_t)n * 64 + lane] + acc;
    float m = wave_sum(r1) * 0.015625f;
    float dv = r1 - m;
    float var = wave_sum(dv * dv) * 0.015625f;
    h1out[(size_t)n * 64 + lane] = dv * rsqrtf(var + 1e-5f) * sb[64 + lane] + sb[128 + lane];
  }
}

// ---------------- Node epilogue 2 (grid-strided): h = LN2(h1 + FFN(h1)) ----------------
__global__ __launch_bounds__(256, 4) void node_epi2_kernel(
    const float* __restrict__ W1, const float* __restrict__ b1,
    const float* __restrict__ W2, const float* __restrict__ b2,
    const float* __restrict__ g2, const float* __restrict__ bb2,
    float* __restrict__ hio) {
  extern __shared__ float sm[];
  float* W1L = sm;
  float* W2L = sm + 8192;
  float* sb = sm + 16384;
  const int tid = threadIdx.x;
  for (int i = tid; i < 8192; i += 256) { W1L[i] = W1[i]; W2L[i] = W2[i]; }
  if (tid < 128) sb[tid] = b1[tid];
  if (tid < 64) { sb[128 + tid] = b2[tid]; sb[192 + tid] = g2[tid]; sb[256 + tid] = bb2[tid]; }
  __syncthreads();
  const int lane = tid & 63;
  for (int nb = blockIdx.x * 16; nb < NN; nb += gridDim.x * 16) {
    const int n0 = nb + (tid >> 6) * 4;
    float h1[4];
#pragma unroll
    for (int j = 0; j < 4; j++)
      h1[j] = (n0 + j < NN) ? hio[(size_t)(n0 + j) * 64 + lane] : 0.f;
    float ua[4], ub[4];
#pragma unroll
    for (int j = 0; j < 4; j++) { ua[j] = sb[lane]; ub[j] = sb[64 + lane]; }
#pragma unroll 4
    for (int k = 0; k < 64; k++) {
      float wa = W1L[k * 128 + lane];
      float wb = W1L[k * 128 + 64 + lane];
#pragma unroll
      for (int j = 0; j < 4; j++) {
        float w = __shfl(h1[j], k);
        ua[j] = fmaf(w, wa, ua[j]);
        ub[j] = fmaf(w, wb, ub[j]);
      }
    }
    float a2[4];
#pragma unroll
    for (int j = 0; j < 4; j++) {
      ua[j] = fmaxf(ua[j], 0.f);
      ub[j] = fmaxf(ub[j], 0.f);
      a2[j] = sb[128 + lane];
    }
#pragma unroll 4
    for (int k = 0; k < 64; k++) {
      float wa = W2L[k * 64 + lane];
      float wb = W2L[(64 + k) * 64 + lane];
#pragma unroll
      for (int j = 0; j < 4; j++) {
        a2[j] = fmaf(__shfl(ua[j], k), wa, a2[j]);
        a2[j] = fmaf(__shfl(ub[j], k), wb, a2[j]);
      }
    }
#pragma unroll
    for (int j = 0; j < 4; j++) {
      if (n0 + j >= NN) continue;
      float r2 = h1[j] + a2[j];
      float m = wave_sum(r2) * 0.015625f;
      float dv = r2 - m;
      float var = wave_sum(dv * dv) * 0.015625f;
      hio[(size_t)(n0 + j) * 64 + lane] = dv * rsqrtf(var + 1e-5f) * sb[192 + lane] + sb[256 + lane];
    }
  }
}

extern "C" void kernel_launch(void* const* d_in, const int* in_sizes, int n_in,
                              void* d_out, int out_size, void* d_ws, size_t ws_size,
                              hipStream_t stream) {
  const float* x = (const float*)d_in[0];
  const float* ea = (const float*)d_in[1];
  const float* log_deg = (const float*)d_in[2];
  const float* Wq = (const float*)d_in[3];
  const float* bq = (const float*)d_in[4];
  const float* Wk = (const float*)d_in[5];
  const float* bk = (const float*)d_in[6];
  const float* Wv = (const float*)d_in[7];
  const float* bv = (const float*)d_in[8];
  const float* We = (const float*)d_in[9];
  const float* be = (const float*)d_in[10];
  const float* Aw = (const float*)d_in[11];
  const float* VeRow = (const float*)d_in[12];
  const float* deg_coef = (const float*)d_in[13];
  const float* Woh = (const float*)d_in[14];
  const float* boh = (const float*)d_in[15];
  const float* Woe = (const float*)d_in[16];
  const float* boe = (const float*)d_in[17];
  const float* g1h = (const float*)d_in[18];
  const float* b1h = (const float*)d_in[19];
  const float* g1e = (const float*)d_in[20];
  const float* b1e = (const float*)d_in[21];
  const float* W1 = (const float*)d_in[22];
  const float* b1 = (const float*)d_in[23];
  const float* W2 = (const float*)d_in[24];
  const float* b2 = (const float*)d_in[25];
  const float* g2h = (const float*)d_in[26];
  const float* b2h = (const float*)d_in[27];
  const int* eidx = (const int*)d_in[28];

  char* p = (char*)d_ws;
  unsigned short* Qh = (unsigned short*)p; p += (size_t)NN * 64 * 2;
  unsigned short* Kh = (unsigned short*)p; p += (size_t)NN * 64 * 2;
  unsigned short* Vh = (unsigned short*)p; p += (size_t)NN * 64 * 2;
  bf16* sE = (bf16*)p;  p += (size_t)NE * 64 * 2;
  float* exE = (float*)p; p += (size_t)NE * 8 * 4;
  int* cnt = (int*)p;   p += ((size_t)NN * 4 + 255) & ~(size_t)255;
  int* rs = (int*)p;    p += (((size_t)NN + 1) * 4 + 255) & ~(size_t)255;
  int* slot = (int*)p;  p += (size_t)NE * 4;
  int* srcs = (int*)p;  p += (size_t)NE * 4;
  int* bsum = (int*)p;  p += ((size_t)SCAN_BLK * 4 + 255) & ~(size_t)255;
  if ((size_t)(p - (char*)d_ws) > ws_size) return;

  float* out_h = (float*)d_out;
  float* out_e = out_h + (size_t)NN * 64;

  hipMemsetAsync(cnt, 0, NN * sizeof(int), stream);
  qkv_hist_kernel<<<QKV_BLOCKS + HIST_BLOCKS, 256, 0, stream>>>(
      x, Wq, bq, Wk, bk, Wv, bv, Qh, Kh, Vh, eidx, cnt);
  scan1_kernel<<<SCAN_BLK, 256, 0, stream>>>(cnt, bsum);
  scan2_kernel<<<1, 64, 0, stream>>>(bsum, rs);
  scan3_kernel<<<SCAN_BLK, 256, 0, stream>>>(cnt, bsum, rs);
  scatter_kernel<<<(NE + 255) / 256, 256, 0, stream>>>(eidx, cnt, slot, srcs);
  edge_kernel<<<1280, 256, 0, stream>>>(ea, We, be, Aw, Woe, boe, g1e, b1e,
                                        Qh, Kh, eidx, slot, sE, exE, out_e);
  node_gather_kernel<<<1024, 256, 0, stream>>>(Vh, sE, exE, srcs, rs, VeRow,
                                               deg_coef, log_deg,
                                               x, Woh, boh, g1h, b1h, out_h);
  node_epi2_kernel<<<512, 256, 16704 * 4, stream>>>(W1, b1, W2, b2, g2h, b2h, out_h);
}